// Round 4
// baseline (400.361 us; speedup 1.0000x reference)
//
#include <hip/hip_runtime.h>
#include <math.h>

// Problem constants (B, L, D, DH from the reference)
#define WS_B  4
#define WS_L  2048
#define WS_D  1024
#define WS_DH 2048
#define WS_M  (WS_B * WS_L)        // 8192 rows (B*L)
#define NCH   32                    // scan chunks per sequence
#define CHUNK (WS_L / NCH)          // 64 timesteps per chunk

typedef __attribute__((ext_vector_type(4))) float     f32x4;
typedef _Float16 f16x8 __attribute__((ext_vector_type(8)));   // MFMA A/B frag (4 VGPRs)
typedef _Float16 f16x4 __attribute__((ext_vector_type(4)));

// ---- round fp32 -> fp16 (single rounding, ~2^-12 rel) ----
__global__ void round_f16(const float* __restrict__ src, _Float16* __restrict__ dst, int n) {
    int i = (blockIdx.x * blockDim.x + threadIdx.x) * 4;
    if (i >= n) return;
    f32x4 v = *(const f32x4*)(src + i);
    f16x4 h4;
#pragma unroll
    for (int k = 0; k < 4; ++k) h4[k] = (_Float16)v[k];
    *(f16x4*)(dst + i) = h4;
}

// ---- round W_out [1024,2048] fp32 -> fp16 duplicated into [1024,4096] (both K-halves) ----
__global__ void round_f16_dup(const float* __restrict__ src, _Float16* __restrict__ dst, int n) {
    int i = (blockIdx.x * blockDim.x + threadIdx.x) * 4;
    if (i >= n) return;
    f32x4 v = *(const f32x4*)(src + i);
    f16x4 h4;
#pragma unroll
    for (int k = 0; k < 4; ++k) h4[k] = (_Float16)v[k];
    int r  = i >> 11;           // row = i / 2048
    int cc = i & 2047;
    _Float16* p = dst + (size_t)r * 4096 + cc;
    *(f16x4*)p = h4;
    *(f16x4*)(p + 2048) = h4;
}

// ---- shared GEMM body: C[m,n] = sum_{k in [koff,koff+Ksz)} A[m,k]*B[n,k] (+bias) ----
// 128x128 tile, BK=32 dbuf, single barrier/kstep, 4 waves (2x2), 4x4 MFMAs 16x16x32.
// launch_bounds(256,4): 4 blocks/CU target (round-3 counters: throughput = residency /
// ~2775-cyc per-block kstep latency; residency is the lever).
__device__ __forceinline__
void gemm_body(const _Float16* __restrict__ A, int lda,
               const _Float16* __restrict__ B, int ldb,
               const float* __restrict__ bias, float* __restrict__ C, int ldc,
               int Ksz, int koff)
{
    __shared__ alignas(16) _Float16 sA[2][4][128][8];
    __shared__ alignas(16) _Float16 sB[2][4][128][8];

    const int tid  = threadIdx.x;
    const int lane = tid & 63;
    const int wave = tid >> 6;
    const int wm   = (wave >> 1) * 64;
    const int wn   = (wave & 1) * 64;
    const int m15  = lane & 15;
    const int q    = lane >> 4;

    const int bm = blockIdx.x;
    const int bn = blockIdx.y;

    const size_t a_base = (size_t)bm * 128 * lda + koff;
    const size_t b_base = (size_t)bn * 128 * ldb + koff;

    f32x4 acc[4][4] = {};

    auto stage = [&](int k0, int buf) {
#pragma unroll
        for (int i = 0; i < 2; ++i) {
            int c   = i * 256 + tid;     // 512 16B chunks per array
            int row = c & 127;
            int kq  = c >> 7;            // wave-uniform
            size_t ga = a_base + (size_t)row * lda + k0 + kq * 8;
            size_t gb = b_base + (size_t)row * ldb + k0 + kq * 8;
            __builtin_amdgcn_global_load_lds(
                (const __attribute__((address_space(1))) unsigned int*)(A + ga),
                (__attribute__((address_space(3))) unsigned int*)&sA[buf][kq][row][0], 16, 0, 0);
            __builtin_amdgcn_global_load_lds(
                (const __attribute__((address_space(1))) unsigned int*)(B + gb),
                (__attribute__((address_space(3))) unsigned int*)&sB[buf][kq][row][0], 16, 0, 0);
        }
    };

    stage(0, 0);
    int buf = 0;
    for (int k0 = 0; k0 < Ksz; k0 += 32, buf ^= 1) {
        __syncthreads();                 // buf ready; buf^1 reads retired
        if (k0 + 32 < Ksz) stage(k0 + 32, buf ^ 1);

        f16x8 af[4], bf[4];
#pragma unroll
        for (int i = 0; i < 4; ++i) {
            af[i] = *(const f16x8*)&sA[buf][q][wm + i * 16 + m15][0];
            bf[i] = *(const f16x8*)&sB[buf][q][wn + i * 16 + m15][0];
        }
#pragma unroll
        for (int i = 0; i < 4; ++i) {
#pragma unroll
            for (int j = 0; j < 4; ++j) {
                acc[i][j] = __builtin_amdgcn_mfma_f32_16x16x32_f16(af[i], bf[j], acc[i][j], 0, 0, 0);
            }
        }
    }

    // epilogue: C/D layout col = lane&15, row = (lane>>4)*4 + reg  (m89-verified)
    const int r4 = (lane >> 4) * 4;
#pragma unroll
    for (int j = 0; j < 4; ++j) {
        int col = bn * 128 + wn + j * 16 + m15;
        float bv = bias ? bias[col] : 0.f;
#pragma unroll
        for (int i = 0; i < 4; ++i) {
            int row0 = bm * 128 + wm + i * 16 + r4;
#pragma unroll
            for (int r = 0; r < 4; ++r) {
                C[(size_t)(row0 + r) * ldc + col] = acc[i][j][r] + bv;
            }
        }
    }
}

// GEMM1: h = x @ W_in^T + b_in.  A[8192,1024], B[2048,1024], grid (64,16) = 1024 blocks.
__global__ __launch_bounds__(256, 4)
void gemm1_f16(const _Float16* __restrict__ A, const _Float16* __restrict__ B,
               const float* __restrict__ bias, float* __restrict__ C)
{
    gemm_body(A, WS_D, B, WS_D, bias, C, WS_DH, WS_D, 0);
}

// GEMM2 split-K: Cpart[z] = y2 @ w2^T over K-half z.  grid (64,8,2) = 1024 blocks.
__global__ __launch_bounds__(256, 4)
void gemm2_f16_splitk(const _Float16* __restrict__ A, const _Float16* __restrict__ B,
                      float* __restrict__ Cpart)
{
    int z = blockIdx.z;
    gemm_body(A, 2 * WS_DH, B, 2 * WS_DH, nullptr,
              Cpart + (size_t)z * WS_M * WS_D, WS_D, WS_DH, z * WS_DH);
}

// fuse: out = c0 + c1 + bias   (8192 x 1024)
__global__ void fuse_add_bias(const float* __restrict__ c0, const float* __restrict__ c1,
                              const float* __restrict__ bias, float* __restrict__ out) {
    int i = (blockIdx.x * blockDim.x + threadIdx.x);
    int e = i * 4;
    if (e >= WS_M * WS_D) return;
    f32x4 a = *(const f32x4*)(c0 + e);
    f32x4 b = *(const f32x4*)(c1 + e);
    f32x4 bv = *(const f32x4*)(bias + (e & (WS_D - 1)));
    f32x4 r = a + b + bv;
    *(f32x4*)(out + e) = r;
}

// ---- scan: U[t] = p*U[t-1] + p0*h[t], U[-1]=last;  z[t]=Re(U[t]); y=silu(z) ----
__device__ inline void compute_p(const float* __restrict__ phazor, int c, float& pre, float& pim) {
    float zr = phazor[2 * c], zi = phazor[2 * c + 1];
    float pa = sqrtf(zr * zr + zi * zi);
    float sc = expf(-pa) / pa;       // unit phase * exp(-|p|) magnitude
    pre = zr * sc;
    pim = zi * sc;
}

// phase 1: per-chunk local scan (init 0), write chunk-end state
__global__ void scan_local(const float* __restrict__ h, const float* __restrict__ phazor,
                           const float* __restrict__ phazor_init, float* __restrict__ Uend) {
    int idx = blockIdx.x * blockDim.x + threadIdx.x;      // [0, B*NCH*DH)
    if (idx >= WS_B * NCH * WS_DH) return;
    int c  = idx & (WS_DH - 1);
    int bj = idx >> 11;
    int j  = bj & (NCH - 1);
    int b  = bj >> 5;
    float pre, pim;
    compute_p(phazor, c, pre, pim);
    float p0r = phazor_init[2 * c], p0i = phazor_init[2 * c + 1];
    const float* hp = h + ((size_t)(b * WS_L + j * CHUNK)) * WS_DH + c;
    float ur = 0.f, ui = 0.f;
    for (int t = 0; t < CHUNK; t += 8) {
        float hv[8];
#pragma unroll
        for (int u = 0; u < 8; ++u) hv[u] = hp[(size_t)(t + u) * WS_DH];
#pragma unroll
        for (int u = 0; u < 8; ++u) {
            float nr = fmaf(pre, ur, fmaf(-pim, ui, p0r * hv[u]));
            float ni = fmaf(pre, ui, fmaf( pim, ur, p0i * hv[u]));
            ur = nr; ui = ni;
        }
    }
    Uend[2 * idx] = ur;
    Uend[2 * idx + 1] = ui;
}

// phase 2: serial combine over chunks; carry[j] = full state entering chunk j
__global__ void scan_carry(const float* __restrict__ Uend, float* __restrict__ carry,
                           const float* __restrict__ phazor,
                           const float* __restrict__ last_re, const float* __restrict__ last_im) {
    int idx = blockIdx.x * blockDim.x + threadIdx.x;      // [0, B*DH)
    if (idx >= WS_B * WS_DH) return;
    int c = idx & (WS_DH - 1);
    int b = idx >> 11;
    float pre, pim;
    compute_p(phazor, c, pre, pim);
    float qr = pre, qi = pim;                              // p^CHUNK via 6 squarings (CHUNK=64)
#pragma unroll
    for (int s = 0; s < 6; ++s) {
        float nr = qr * qr - qi * qi;
        qi = 2.f * qr * qi;
        qr = nr;
    }
    float ur = last_re[idx], ui = last_im[idx];            // U[-1] = last
    for (int j = 0; j < NCH; ++j) {
        int o = (b * NCH + j) * WS_DH + c;
        carry[2 * o] = ur;
        carry[2 * o + 1] = ui;
        float Lr = Uend[2 * o], Li = Uend[2 * o + 1];
        float nr = fmaf(qr, ur, fmaf(-qi, ui, Lr));
        float ni = fmaf(qr, ui, fmaf( qi, ur, Li));
        ur = nr; ui = ni;
    }
}

// phase 3: re-scan each chunk from its carry, apply silu, write y split (hi|lo)
// into the K-doubled fp16 activation y2[8192, 4096]: cols [0,2048)=hi, [2048,4096)=lo.
__global__ void scan_apply(const float* __restrict__ h, const float* __restrict__ phazor,
                           const float* __restrict__ phazor_init, const float* __restrict__ carry,
                           _Float16* __restrict__ y2) {
    int idx = blockIdx.x * blockDim.x + threadIdx.x;
    if (idx >= WS_B * NCH * WS_DH) return;
    int c  = idx & (WS_DH - 1);
    int bj = idx >> 11;
    int j  = bj & (NCH - 1);
    int b  = bj >> 5;
    float pre, pim;
    compute_p(phazor, c, pre, pim);
    float p0r = phazor_init[2 * c], p0i = phazor_init[2 * c + 1];
    float ur = carry[2 * idx], ui = carry[2 * idx + 1];
    const int row0 = b * WS_L + j * CHUNK;
    const float* hp = h + (size_t)row0 * WS_DH + c;
    for (int t = 0; t < CHUNK; t += 8) {
        float hv[8];
#pragma unroll
        for (int u = 0; u < 8; ++u) hv[u] = hp[(size_t)(t + u) * WS_DH];
#pragma unroll
        for (int u = 0; u < 8; ++u) {
            float nr = fmaf(pre, ur, fmaf(-pim, ui, p0r * hv[u]));
            float ni = fmaf(pre, ui, fmaf( pim, ur, p0i * hv[u]));
            ur = nr; ui = ni;
            float z  = ur;                                  // Re(U[t])
            float yv = z / (1.f + expf(-z));                // silu
            _Float16 hh = (_Float16)yv;
            size_t o = (size_t)(row0 + t + u) * (2 * WS_DH) + c;
            y2[o] = hh;
            y2[o + WS_DH] = (_Float16)(yv - (float)hh);
        }
    }
}

extern "C" void kernel_launch(void* const* d_in, const int* in_sizes, int n_in,
                              void* d_out, int out_size, void* d_ws, size_t ws_size,
                              hipStream_t stream)
{
    const float* x       = (const float*)d_in[0];
    const float* W_in    = (const float*)d_in[1];
    const float* b_in    = (const float*)d_in[2];
    const float* W_out   = (const float*)d_in[3];
    const float* b_out   = (const float*)d_in[4];
    const float* phazor  = (const float*)d_in[5];
    const float* ph_init = (const float*)d_in[6];
    const float* last_re = (const float*)d_in[7];
    const float* last_im = (const float*)d_in[8];
    float* out = (float*)d_out;

    // workspace carve-up (~225 MB)
    char* ws = (char*)d_ws;
    size_t off = 0;
    auto alloc = [&](size_t bytes) {
        char* p = ws + off;
        off += (bytes + 255) & ~(size_t)255;
        return p;
    };
    _Float16* xh    = (_Float16*)alloc((size_t)WS_M * WS_D * 2);           // 16 MB
    _Float16* w1    = (_Float16*)alloc((size_t)WS_DH * WS_D * 2);          //  4 MB
    _Float16* w2    = (_Float16*)alloc((size_t)WS_D * 2 * WS_DH * 2);      //  8 MB (dup K-halves)
    float*    h     = (float*)alloc((size_t)WS_M * WS_DH * 4);             // 64 MB
    _Float16* y2    = (_Float16*)alloc((size_t)WS_M * 2 * WS_DH * 2);      // 64 MB (hi|lo)
    float*    cpart = (float*)alloc((size_t)2 * WS_M * WS_D * 4);          // 64 MB (split-K)
    float*    Uend  = (float*)alloc((size_t)WS_B * NCH * WS_DH * 2 * 4);
    float*    carry = (float*)alloc((size_t)WS_B * NCH * WS_DH * 2 * 4);

    // 1) round inputs to fp16
    {
        int n = WS_M * WS_D;
        round_f16<<<dim3(n / 4 / 256), dim3(256), 0, stream>>>(x, xh, n);
        n = WS_DH * WS_D;
        round_f16<<<dim3(n / 4 / 256), dim3(256), 0, stream>>>(W_in, w1, n);
        n = WS_D * WS_DH;
        round_f16_dup<<<dim3(n / 4 / 256), dim3(256), 0, stream>>>(W_out, w2, n);
    }

    // 2) h = x @ W_in^T + b_in   [8192, 2048], grid 64x16 = 1024 blocks
    {
        dim3 g(WS_M / 128, WS_DH / 128);
        gemm1_f16<<<g, dim3(256), 0, stream>>>(xh, w1, b_in, h);
    }

    // 3) chunked complex scan + silu -> y2 (fp16 hi|lo along K)
    {
        int total = WS_B * NCH * WS_DH;
        scan_local<<<dim3(total / 256), dim3(256), 0, stream>>>(h, phazor, ph_init, Uend);
        scan_carry<<<dim3(WS_B * WS_DH / 256), dim3(256), 0, stream>>>(Uend, carry, phazor,
                                                                       last_re, last_im);
        scan_apply<<<dim3(total / 256), dim3(256), 0, stream>>>(h, phazor, ph_init, carry, y2);
    }

    // 4) split-K GEMM2: cpart[z] = y2 @ w2^T (K-half z), grid 64x8x2 = 1024 blocks
    {
        dim3 g(WS_M / 128, WS_D / 128, 2);
        gemm2_f16_splitk<<<g, dim3(256), 0, stream>>>(y2, w2, cpart);
    }

    // 5) out = cpart0 + cpart1 + b_out
    {
        int n = WS_M * WS_D;
        fuse_add_bias<<<dim3(n / 4 / 256), dim3(256), 0, stream>>>(
            cpart, cpart + (size_t)WS_M * WS_D, b_out, out);
    }
}

// Round 5
// 353.669 us; speedup vs baseline: 1.1320x; 1.1320x over previous
//
#include <hip/hip_runtime.h>
#include <math.h>

// Problem constants (B, L, D, DH from the reference)
#define WS_B  4
#define WS_L  2048
#define WS_D  1024
#define WS_DH 2048
#define WS_M  (WS_B * WS_L)        // 8192 rows (B*L)
#define NCH   32                    // scan chunks per sequence
#define CHUNK (WS_L / NCH)          // 64 timesteps per chunk

typedef __attribute__((ext_vector_type(4))) float     f32x4;
typedef _Float16 f16x8 __attribute__((ext_vector_type(8)));   // MFMA A/B frag (4 VGPRs)
typedef _Float16 f16x4 __attribute__((ext_vector_type(4)));

// ---- round fp32 -> fp16 (single rounding, ~2^-12 rel) ----
__global__ void round_f16(const float* __restrict__ src, _Float16* __restrict__ dst, int n) {
    int i = (blockIdx.x * blockDim.x + threadIdx.x) * 4;
    if (i >= n) return;
    f32x4 v = *(const f32x4*)(src + i);
    f16x4 h4;
#pragma unroll
    for (int k = 0; k < 4; ++k) h4[k] = (_Float16)v[k];
    *(f16x4*)(dst + i) = h4;
}

// GEMM1: h = x @ W_in^T + b_in.  128x128 tile, BK=32 dbuf, single barrier/kstep.
// Staged 16 KB per block-kstep; model: P ~= bytes / (11.5 B/cyc/CU).
__global__ __launch_bounds__(256, 4)
void gemm1_f16(const _Float16* __restrict__ A, const _Float16* __restrict__ B,
               const float* __restrict__ bias, float* __restrict__ C)
{
    const int K = WS_D, ldc = WS_DH;
    __shared__ alignas(16) _Float16 sA[2][4][128][8];
    __shared__ alignas(16) _Float16 sB[2][4][128][8];

    const int tid  = threadIdx.x;
    const int lane = tid & 63;
    const int wave = tid >> 6;
    const int wm   = (wave >> 1) * 64;
    const int wn   = (wave & 1) * 64;
    const int m15  = lane & 15;
    const int q    = lane >> 4;

    const int bm = blockIdx.x;
    const int bn = blockIdx.y;
    const size_t a_base = (size_t)bm * 128 * K;
    const size_t b_base = (size_t)bn * 128 * K;

    f32x4 acc[4][4] = {};

    auto stage = [&](int k0, int buf) {
#pragma unroll
        for (int i = 0; i < 2; ++i) {
            int c   = i * 256 + tid;     // 512 16B chunks per array
            int row = c & 127;
            int kq  = c >> 7;            // wave-uniform
            size_t ga = a_base + (size_t)row * K + k0 + kq * 8;
            size_t gb = b_base + (size_t)row * K + k0 + kq * 8;
            __builtin_amdgcn_global_load_lds(
                (const __attribute__((address_space(1))) unsigned int*)(A + ga),
                (__attribute__((address_space(3))) unsigned int*)&sA[buf][kq][row][0], 16, 0, 0);
            __builtin_amdgcn_global_load_lds(
                (const __attribute__((address_space(1))) unsigned int*)(B + gb),
                (__attribute__((address_space(3))) unsigned int*)&sB[buf][kq][row][0], 16, 0, 0);
        }
    };

    stage(0, 0);
    int buf = 0;
    for (int k0 = 0; k0 < K; k0 += 32, buf ^= 1) {
        __syncthreads();
        if (k0 + 32 < K) stage(k0 + 32, buf ^ 1);

        f16x8 af[4], bf[4];
#pragma unroll
        for (int i = 0; i < 4; ++i) {
            af[i] = *(const f16x8*)&sA[buf][q][wm + i * 16 + m15][0];
            bf[i] = *(const f16x8*)&sB[buf][q][wn + i * 16 + m15][0];
        }
#pragma unroll
        for (int i = 0; i < 4; ++i) {
#pragma unroll
            for (int j = 0; j < 4; ++j) {
                acc[i][j] = __builtin_amdgcn_mfma_f32_16x16x32_f16(af[i], bf[j], acc[i][j], 0, 0, 0);
            }
        }
    }

    const int r4 = (lane >> 4) * 4;   // C/D: col=lane&15, row=(lane>>4)*4+reg (m89)
#pragma unroll
    for (int j = 0; j < 4; ++j) {
        int col = bn * 128 + wn + j * 16 + m15;
        float bv = bias[col];
#pragma unroll
        for (int i = 0; i < 4; ++i) {
            int row0 = bm * 128 + wm + i * 16 + r4;
#pragma unroll
            for (int r = 0; r < 4; ++r) {
                C[(size_t)(row0 + r) * ldc + col] = acc[i][j][r] + bv;
            }
        }
    }
}

// GEMM2 shared-B: out = (yh + yl) @ W^T + bias, K=2048, W staged ONCE per kstep.
// Per kstep: stage yh 8K + yl 8K + W 8K = 24 KB for 32 MFMA/wave (vs 32 KB in the
// K-doubled formulation) -- 25% fewer staged bytes per FLOP under the byte-rate model.
__global__ __launch_bounds__(256, 2)
void gemm2_f16(const _Float16* __restrict__ Ah, const _Float16* __restrict__ Al,
               const _Float16* __restrict__ B,
               const float* __restrict__ bias, float* __restrict__ C)
{
    const int K = WS_DH, ldc = WS_D;
    __shared__ alignas(16) _Float16 sAh[2][4][128][8];
    __shared__ alignas(16) _Float16 sAl[2][4][128][8];
    __shared__ alignas(16) _Float16 sB [2][4][128][8];

    const int tid  = threadIdx.x;
    const int lane = tid & 63;
    const int wave = tid >> 6;
    const int wm   = (wave >> 1) * 64;
    const int wn   = (wave & 1) * 64;
    const int m15  = lane & 15;
    const int q    = lane >> 4;

    const int bm = blockIdx.x;
    const int bn = blockIdx.y;
    const size_t a_base = (size_t)bm * 128 * K;
    const size_t b_base = (size_t)bn * 128 * K;

    f32x4 acc[4][4] = {};

    auto stage = [&](int k0, int buf) {
#pragma unroll
        for (int i = 0; i < 2; ++i) {
            int c   = i * 256 + tid;
            int row = c & 127;
            int kq  = c >> 7;
            size_t ga = a_base + (size_t)row * K + k0 + kq * 8;
            size_t gb = b_base + (size_t)row * K + k0 + kq * 8;
            __builtin_amdgcn_global_load_lds(
                (const __attribute__((address_space(1))) unsigned int*)(Ah + ga),
                (__attribute__((address_space(3))) unsigned int*)&sAh[buf][kq][row][0], 16, 0, 0);
            __builtin_amdgcn_global_load_lds(
                (const __attribute__((address_space(1))) unsigned int*)(Al + ga),
                (__attribute__((address_space(3))) unsigned int*)&sAl[buf][kq][row][0], 16, 0, 0);
            __builtin_amdgcn_global_load_lds(
                (const __attribute__((address_space(1))) unsigned int*)(B + gb),
                (__attribute__((address_space(3))) unsigned int*)&sB[buf][kq][row][0], 16, 0, 0);
        }
    };

    stage(0, 0);
    int buf = 0;
    for (int k0 = 0; k0 < K; k0 += 32, buf ^= 1) {
        __syncthreads();
        if (k0 + 32 < K) stage(k0 + 32, buf ^ 1);

        f16x8 afh[4], afl[4], bf[4];
#pragma unroll
        for (int i = 0; i < 4; ++i) {
            afh[i] = *(const f16x8*)&sAh[buf][q][wm + i * 16 + m15][0];
            afl[i] = *(const f16x8*)&sAl[buf][q][wm + i * 16 + m15][0];
            bf[i]  = *(const f16x8*)&sB [buf][q][wn + i * 16 + m15][0];
        }
#pragma unroll
        for (int i = 0; i < 4; ++i) {
#pragma unroll
            for (int j = 0; j < 4; ++j) {
                acc[i][j] = __builtin_amdgcn_mfma_f32_16x16x32_f16(afh[i], bf[j], acc[i][j], 0, 0, 0);
                acc[i][j] = __builtin_amdgcn_mfma_f32_16x16x32_f16(afl[i], bf[j], acc[i][j], 0, 0, 0);
            }
        }
    }

    const int r4 = (lane >> 4) * 4;
#pragma unroll
    for (int j = 0; j < 4; ++j) {
        int col = bn * 128 + wn + j * 16 + m15;
        float bv = bias[col];
#pragma unroll
        for (int i = 0; i < 4; ++i) {
            int row0 = bm * 128 + wm + i * 16 + r4;
#pragma unroll
            for (int r = 0; r < 4; ++r) {
                C[(size_t)(row0 + r) * ldc + col] = acc[i][j][r] + bv;
            }
        }
    }
}

// ---- scan: U[t] = p*U[t-1] + p0*h[t], U[-1]=last;  z[t]=Re(U[t]); y=silu(z) ----
__device__ inline void compute_p(const float* __restrict__ phazor, int c, float& pre, float& pim) {
    float zr = phazor[2 * c], zi = phazor[2 * c + 1];
    float pa = sqrtf(zr * zr + zi * zi);
    float sc = expf(-pa) / pa;       // unit phase * exp(-|p|) magnitude
    pre = zr * sc;
    pim = zi * sc;
}

// phase 1: per-chunk local scan (init 0), write chunk-end state
__global__ void scan_local(const float* __restrict__ h, const float* __restrict__ phazor,
                           const float* __restrict__ phazor_init, float* __restrict__ Uend) {
    int idx = blockIdx.x * blockDim.x + threadIdx.x;      // [0, B*NCH*DH)
    if (idx >= WS_B * NCH * WS_DH) return;
    int c  = idx & (WS_DH - 1);
    int bj = idx >> 11;
    int j  = bj & (NCH - 1);
    int b  = bj >> 5;
    float pre, pim;
    compute_p(phazor, c, pre, pim);
    float p0r = phazor_init[2 * c], p0i = phazor_init[2 * c + 1];
    const float* hp = h + ((size_t)(b * WS_L + j * CHUNK)) * WS_DH + c;
    float ur = 0.f, ui = 0.f;
    for (int t = 0; t < CHUNK; t += 8) {
        float hv[8];
#pragma unroll
        for (int u = 0; u < 8; ++u) hv[u] = hp[(size_t)(t + u) * WS_DH];
#pragma unroll
        for (int u = 0; u < 8; ++u) {
            float nr = fmaf(pre, ur, fmaf(-pim, ui, p0r * hv[u]));
            float ni = fmaf(pre, ui, fmaf( pim, ur, p0i * hv[u]));
            ur = nr; ui = ni;
        }
    }
    Uend[2 * idx] = ur;
    Uend[2 * idx + 1] = ui;
}

// phase 2: serial combine over chunks; carry[j] = full state entering chunk j
__global__ void scan_carry(const float* __restrict__ Uend, float* __restrict__ carry,
                           const float* __restrict__ phazor,
                           const float* __restrict__ last_re, const float* __restrict__ last_im) {
    int idx = blockIdx.x * blockDim.x + threadIdx.x;      // [0, B*DH)
    if (idx >= WS_B * WS_DH) return;
    int c = idx & (WS_DH - 1);
    int b = idx >> 11;
    float pre, pim;
    compute_p(phazor, c, pre, pim);
    float qr = pre, qi = pim;                              // p^CHUNK via 6 squarings (CHUNK=64)
#pragma unroll
    for (int s = 0; s < 6; ++s) {
        float nr = qr * qr - qi * qi;
        qi = 2.f * qr * qi;
        qr = nr;
    }
    float ur = last_re[idx], ui = last_im[idx];            // U[-1] = last
    for (int j = 0; j < NCH; ++j) {
        int o = (b * NCH + j) * WS_DH + c;
        carry[2 * o] = ur;
        carry[2 * o + 1] = ui;
        float Lr = Uend[2 * o], Li = Uend[2 * o + 1];
        float nr = fmaf(qr, ur, fmaf(-qi, ui, Lr));
        float ni = fmaf(qr, ui, fmaf( qi, ur, Li));
        ur = nr; ui = ni;
    }
}

// phase 3: re-scan each chunk from its carry, apply silu, write y as fp16 hi/lo
// into two separate [8192,2048] arrays (GEMM2 stages them as two A-operands).
__global__ void scan_apply(const float* __restrict__ h, const float* __restrict__ phazor,
                           const float* __restrict__ phazor_init, const float* __restrict__ carry,
                           _Float16* __restrict__ yh, _Float16* __restrict__ yl) {
    int idx = blockIdx.x * blockDim.x + threadIdx.x;
    if (idx >= WS_B * NCH * WS_DH) return;
    int c  = idx & (WS_DH - 1);
    int bj = idx >> 11;
    int j  = bj & (NCH - 1);
    int b  = bj >> 5;
    float pre, pim;
    compute_p(phazor, c, pre, pim);
    float p0r = phazor_init[2 * c], p0i = phazor_init[2 * c + 1];
    float ur = carry[2 * idx], ui = carry[2 * idx + 1];
    const size_t base = ((size_t)(b * WS_L + j * CHUNK)) * WS_DH + c;
    const float* hp = h + base;
    for (int t = 0; t < CHUNK; t += 8) {
        float hv[8];
#pragma unroll
        for (int u = 0; u < 8; ++u) hv[u] = hp[(size_t)(t + u) * WS_DH];
#pragma unroll
        for (int u = 0; u < 8; ++u) {
            float nr = fmaf(pre, ur, fmaf(-pim, ui, p0r * hv[u]));
            float ni = fmaf(pre, ui, fmaf( pim, ur, p0i * hv[u]));
            ur = nr; ui = ni;
            float z  = ur;                                  // Re(U[t])
            float yv = z / (1.f + expf(-z));                // silu
            _Float16 hh = (_Float16)yv;
            size_t o = base + (size_t)(t + u) * WS_DH;
            yh[o] = hh;
            yl[o] = (_Float16)(yv - (float)hh);
        }
    }
}

extern "C" void kernel_launch(void* const* d_in, const int* in_sizes, int n_in,
                              void* d_out, int out_size, void* d_ws, size_t ws_size,
                              hipStream_t stream)
{
    const float* x       = (const float*)d_in[0];
    const float* W_in    = (const float*)d_in[1];
    const float* b_in    = (const float*)d_in[2];
    const float* W_out   = (const float*)d_in[3];
    const float* b_out   = (const float*)d_in[4];
    const float* phazor  = (const float*)d_in[5];
    const float* ph_init = (const float*)d_in[6];
    const float* last_re = (const float*)d_in[7];
    const float* last_im = (const float*)d_in[8];
    float* out = (float*)d_out;

    // workspace carve-up (~156 MB)
    char* ws = (char*)d_ws;
    size_t off = 0;
    auto alloc = [&](size_t bytes) {
        char* p = ws + off;
        off += (bytes + 255) & ~(size_t)255;
        return p;
    };
    _Float16* xh    = (_Float16*)alloc((size_t)WS_M * WS_D * 2);     // 16 MB
    _Float16* w1    = (_Float16*)alloc((size_t)WS_DH * WS_D * 2);    //  4 MB
    _Float16* w2    = (_Float16*)alloc((size_t)WS_D * WS_DH * 2);    //  4 MB
    float*    h     = (float*)alloc((size_t)WS_M * WS_DH * 4);       // 64 MB
    _Float16* yh    = (_Float16*)alloc((size_t)WS_M * WS_DH * 2);    // 32 MB
    _Float16* yl    = (_Float16*)alloc((size_t)WS_M * WS_DH * 2);    // 32 MB
    float*    Uend  = (float*)alloc((size_t)WS_B * NCH * WS_DH * 2 * 4);
    float*    carry = (float*)alloc((size_t)WS_B * NCH * WS_DH * 2 * 4);

    // 1) round inputs to fp16
    {
        int n = WS_M * WS_D;
        round_f16<<<dim3(n / 4 / 256), dim3(256), 0, stream>>>(x, xh, n);
        n = WS_DH * WS_D;
        round_f16<<<dim3(n / 4 / 256), dim3(256), 0, stream>>>(W_in, w1, n);
        n = WS_D * WS_DH;
        round_f16<<<dim3(n / 4 / 256), dim3(256), 0, stream>>>(W_out, w2, n);
    }

    // 2) h = x @ W_in^T + b_in   [8192, 2048], grid 64x16 = 1024 blocks
    {
        dim3 g(WS_M / 128, WS_DH / 128);
        gemm1_f16<<<g, dim3(256), 0, stream>>>(xh, w1, b_in, h);
    }

    // 3) chunked complex scan + silu -> yh/yl (fp16)
    {
        int total = WS_B * NCH * WS_DH;
        scan_local<<<dim3(total / 256), dim3(256), 0, stream>>>(h, phazor, ph_init, Uend);
        scan_carry<<<dim3(WS_B * WS_DH / 256), dim3(256), 0, stream>>>(Uend, carry, phazor,
                                                                       last_re, last_im);
        scan_apply<<<dim3(total / 256), dim3(256), 0, stream>>>(h, phazor, ph_init, carry, yh, yl);
    }

    // 4) out = (yh + yl) @ W_out^T + b_out, K=2048, grid 64x8 = 512 blocks
    {
        dim3 g(WS_M / 128, WS_D / 128);
        gemm2_f16<<<g, dim3(256), 0, stream>>>(yh, yl, w2, b_out, out);
    }
}